// Round 8
// baseline (522.354 us; speedup 1.0000x reference)
//
#include <hip/hip_runtime.h>
#include <hip/hip_bf16.h>
#include <math.h>

#define NEG_SLOPE 0.2f

constexpr int N_NODES = 50000;
constexpr int F_IN    = 512;
constexpr int HID     = 128;
constexpr int H1      = 4;
constexpr int E_EDGES = 800000;
constexpr int E_TOT   = E_EDGES + N_NODES;  // 850000 (self loops appended)

typedef __attribute__((ext_vector_type(8))) short short8;     // 8 bf16 = 4 VGPRs (MFMA frag)
typedef __attribute__((ext_vector_type(4))) float floatx4;    // MFMA acc
typedef __attribute__((ext_vector_type(4))) unsigned short ushort4v;

// fp32 -> bf16 round-to-nearest-even (finite inputs)
__device__ __forceinline__ unsigned short f2bf(float f) {
  union { float f; unsigned int u; } v; v.f = f;
  unsigned int u = v.u + 0x7FFFu + ((v.u >> 16) & 1u);
  return (unsigned short)(u >> 16);
}
__device__ __forceinline__ float bf_lo(unsigned int u) {
  union { unsigned int u; float f; } v; v.u = u << 16; return v.f;
}
__device__ __forceinline__ float bf_hi(unsigned int u) {
  union { unsigned int u; float f; } v; v.u = u & 0xFFFF0000u; return v.f;
}

__device__ __forceinline__ void store_val(float* p, float v) { *p = v; }
__device__ __forceinline__ void store_val(unsigned short* p, float v) { *p = f2bf(v); }

template <int CPT>
__device__ __forceinline__ void store_vec(unsigned short* p, const float* v) {
#pragma unroll
  for (int c = 0; c < CPT; c += 4) {
    ushort4v o;
#pragma unroll
    for (int j = 0; j < 4; ++j) o[j] = f2bf(v[c + j]);
    *(ushort4v*)(p + c) = o;
  }
}
template <int CPT>
__device__ __forceinline__ void store_vec(float* p, const float* v) {
#pragma unroll
  for (int c = 0; c < CPT; c += 4) *(float4*)(p + c) = *(const float4*)(v + c);
}

__device__ __forceinline__ void async_load16(const void* g, void* lds) {
  __builtin_amdgcn_global_load_lds(
      (const __attribute__((address_space(1))) unsigned int*)g,
      (__attribute__((address_space(3))) unsigned int*)lds, 16, 0, 0);
}

// ---------------- utility ----------------
__global__ void zero_int_kernel(int* p, int n) {
  int i = blockIdx.x * blockDim.x + threadIdx.x;
  if (i < n) p[i] = 0;
}

__global__ void hist_kernel(const int* __restrict__ ei, int* __restrict__ counts) {
  int i = blockIdx.x * blockDim.x + threadIdx.x;
  if (i < E_EDGES) {
    atomicAdd(&counts[ei[E_EDGES + i]], 1);
  } else if (i < E_TOT) {
    atomicAdd(&counts[i - E_EDGES], 1);
  }
}

// ---------------- hierarchical exclusive scan (3 kernels) ----------------
__global__ void scan1_kernel(const int* __restrict__ cnt, int* __restrict__ part,
                             int* __restrict__ bsum, int n) {
  __shared__ int buf[256];
  int tid = threadIdx.x, i = blockIdx.x * 256 + tid;
  int v = (i < n) ? cnt[i] : 0;
  buf[tid] = v;
  __syncthreads();
  for (int s = 1; s < 256; s <<= 1) {
    int t = (tid >= s) ? buf[tid - s] : 0;
    __syncthreads();
    buf[tid] += t;
    __syncthreads();
  }
  if (i < n) part[i] = buf[tid] - v;
  if (tid == 255) bsum[blockIdx.x] = buf[255];
}

__global__ void scan2_kernel(int* __restrict__ bsum, int nb) {  // nb <= 256, single block
  __shared__ int buf[256];
  int tid = threadIdx.x;
  int v = (tid < nb) ? bsum[tid] : 0;
  buf[tid] = v;
  __syncthreads();
  for (int s = 1; s < 256; s <<= 1) {
    int t = (tid >= s) ? buf[tid - s] : 0;
    __syncthreads();
    buf[tid] += t;
    __syncthreads();
  }
  if (tid < nb) bsum[tid] = buf[tid] - v;   // exclusive
  if (tid == 255) bsum[nb] = buf[255];      // total
}

// also zeroes cursor for the scatter pass
__global__ void scan3_kernel(const int* __restrict__ part, const int* __restrict__ bsum,
                             int* __restrict__ offs, int* __restrict__ cursor, int n) {
  int i = blockIdx.x * 256 + threadIdx.x;
  if (i < n) { offs[i] = part[i] + bsum[blockIdx.x]; cursor[i] = 0; }
  if (i == 0) offs[n] = bsum[(n + 255) / 256];
}

__global__ void scatter_kernel(const int* __restrict__ ei, const int* __restrict__ offs,
                               int* __restrict__ cursor, int* __restrict__ sorted_src) {
  int i = blockIdx.x * blockDim.x + threadIdx.x;
  if (i >= E_TOT) return;
  int s, d;
  if (i < E_EDGES) { s = ei[i]; d = ei[E_EDGES + i]; }
  else             { s = i - E_EDGES; d = s; }
  int pos = offs[d] + atomicAdd(&cursor[d], 1);
  sorted_src[pos] = s;
}

// in [K][N] fp32 -> out [N][K] bf16
__global__ void tcast_kernel(const float* __restrict__ in, unsigned short* __restrict__ out,
                             int K, int N) {
  int idx = blockIdx.x * blockDim.x + threadIdx.x;
  if (idx >= K * N) return;
  int n = idx / K, k = idx - n * K;
  out[idx] = f2bf(in[k * N + n]);
}

// ---------------- bf16 MFMA GEMM + fused alpha-dot epilogue ----------------
// CVT_A: A is fp32, converted to bf16 during LDS staging (fuses the cast kernel).
// Grid is 1D, swizzled so the Hn head-blocks of a row-tile share an XCD (id mod 8).
template <bool CVT_A, typename OT>
__global__ __launch_bounds__(256) void gemm_bf16_kernel(
    const void* __restrict__ Araw, const unsigned short* __restrict__ Bt,
    OT* __restrict__ C, const float* __restrict__ a_srcp, const float* __restrict__ a_dstp,
    float* __restrict__ alpha_src, float* __restrict__ alpha_dst,
    int M, int N, int K, int Hn, int nRowTiles) {
  __shared__ unsigned short As[128 * 32];  // [row][k] 8 KB
  __shared__ unsigned short Bs[128 * 32];
  __shared__ float red_s[128][2];
  __shared__ float red_d[128][2];

  int grp = blockIdx.x / (8 * Hn);
  int w8 = blockIdx.x % (8 * Hn);
  int head = w8 >> 3;
  int rowTile = grp * 8 + (w8 & 7);
  if (rowTile >= nRowTiles) return;    // whole block exits together (uniform)
  int row0 = rowTile * 128;
  int col0 = head * 128;

  int tid = threadIdx.x;
  int lane = tid & 63, wave = tid >> 6;
  int wm = wave & 1, wn = wave >> 1;
  int l15 = lane & 15, quad = lane >> 4;

  floatx4 acc[4][4];
#pragma unroll
  for (int i = 0; i < 4; ++i)
#pragma unroll
    for (int j = 0; j < 4; ++j) acc[i][j] = (floatx4){0.f, 0.f, 0.f, 0.f};

  int seg_b = wave * 2;
  int r_in = (lane >> 2);
  int c8 = (lane & 3) * 8;

  for (int k0 = 0; k0 < K; k0 += 32) {
    // ---- B tile: async global->LDS (8 segments of 512B over 4 waves) ----
#pragma unroll
    for (int p = 0; p < 2; ++p) {
      int seg = seg_b + p;
      int r = seg * 16 + r_in;
      int gc = col0 + r;                        // N multiple of 128
      async_load16(Bt + (size_t)gc * K + k0 + c8, &Bs[seg * 512]);
    }
    // ---- A tile ----
    if constexpr (CVT_A) {
      // 128 rows x 32 k-elems = 1024 float4 slots; 256 thr x 4 iters.
      const float* Af = (const float*)Araw;
#pragma unroll
      for (int p = 0; p < 4; ++p) {
        int lin = tid + p * 256;            // 0..1023
        int r = lin >> 3;                   // 0..127
        int q = lin & 7;                    // 0..7 (k-quad of 4 fp32)
        int gr = row0 + r; if (gr >= M) gr = M - 1;
        float4 f = *(const float4*)(Af + (size_t)gr * K + k0 + q * 4);
        ushort4v o;
        o[0] = f2bf(f.x); o[1] = f2bf(f.y); o[2] = f2bf(f.z); o[3] = f2bf(f.w);
        *(ushort4v*)&As[r * 32 + q * 4] = o;
      }
    } else {
      const unsigned short* Ab = (const unsigned short*)Araw;
#pragma unroll
      for (int p = 0; p < 2; ++p) {
        int seg = seg_b + p;
        int r = seg * 16 + r_in;
        int gr = row0 + r; if (gr >= M) gr = M - 1;
        async_load16(Ab + (size_t)gr * K + k0 + c8, &As[seg * 512]);
      }
    }
    __syncthreads();

    short8 a[4], b[4];
#pragma unroll
    for (int mi = 0; mi < 4; ++mi)
      a[mi] = *(const short8*)&As[(wm * 64 + mi * 16 + l15) * 32 + quad * 8];
#pragma unroll
    for (int ni = 0; ni < 4; ++ni)
      b[ni] = *(const short8*)&Bs[(wn * 64 + ni * 16 + l15) * 32 + quad * 8];
#pragma unroll
    for (int mi = 0; mi < 4; ++mi)
#pragma unroll
      for (int ni = 0; ni < 4; ++ni)
        acc[mi][ni] = __builtin_amdgcn_mfma_f32_16x16x32_bf16(a[mi], b[ni], acc[mi][ni], 0, 0, 0);
    __syncthreads();
  }

  float a_s[4], a_d[4];
#pragma unroll
  for (int ni = 0; ni < 4; ++ni) {
    int cih = wn * 64 + ni * 16 + l15;
    a_s[ni] = a_srcp[head * HID + cih];
    a_d[ni] = a_dstp[head * HID + cih];
  }

#pragma unroll
  for (int mi = 0; mi < 4; ++mi) {
#pragma unroll
    for (int r = 0; r < 4; ++r) {
      int rloc = wm * 64 + mi * 16 + quad * 4 + r;
      int grow = row0 + rloc;
      float ps = 0.f, pd = 0.f;
#pragma unroll
      for (int ni = 0; ni < 4; ++ni) {
        float v = acc[mi][ni][r];
        ps += v * a_s[ni];
        pd += v * a_d[ni];
        if (grow < M) {
          int gcol = col0 + wn * 64 + ni * 16 + l15;
          store_val(&C[(size_t)grow * N + gcol], v);
        }
      }
#pragma unroll
      for (int off = 1; off < 16; off <<= 1) {
        ps += __shfl_xor(ps, off);
        pd += __shfl_xor(pd, off);
      }
      if (l15 == 0) { red_s[rloc][wn] = ps; red_d[rloc][wn] = pd; }
    }
  }
  __syncthreads();
  if (tid < 128) {
    int grow = row0 + tid;
    if (grow < M) {
      alpha_src[(size_t)grow * Hn + head] = red_s[tid][0] + red_s[tid][1];
      alpha_dst[(size_t)grow * Hn + head] = red_d[tid][0] + red_d[tid][1];
    }
  }
}

// ---------------- segment softmax + weighted aggregation ----------------
// Block = 128 threads = 2 INDEPENDENT waves (no cross-wave data flow; softmax is
// recomputed per wave; per-wave LDS slices).
//   WPN=2: both waves serve the SAME node, each covering CH/2 channels
//          (doubles loads-in-flight per node; used for H=4, CH=512).
//   WPN=1: each wave serves its OWN node (used for H=1, CH=128).
// deg <= 64 (Poisson(16)+1). bf16 gather rows, exact fp32 accumulate.
template <int H, int WPN, typename OT>
__global__ __launch_bounds__(128) void aggregate_kernel(
    const unsigned short* __restrict__ h, const float* __restrict__ asrc,
    const float* __restrict__ adst, const int* __restrict__ offs,
    const int* __restrict__ sorted_src, const float* __restrict__ bias,
    OT* __restrict__ out, int apply_elu) {
  constexpr int CPT = 8;
  constexpr int CH = H * HID;
  constexpr int WCH = CH / WPN;        // channels this wave covers
  constexpr int NCH = WCH / CPT;       // lanes covering channels
  constexpr int SLOTS = 64 / NCH;      // edge slots per wave
  __shared__ float p_sh[2][64 * H];
  __shared__ int ro_sh[2][64];         // src * CH (fits int: 50000*512)
  int tid = threadIdx.x;
  int lane = tid & 63, w = tid >> 6;
  int node = (WPN == 2) ? blockIdx.x : blockIdx.x * 2 + w;
  bool live = node < N_NODES;
  int off = live ? offs[node] : 0;
  int deg = live ? (offs[node + 1] - off) : 0;
  if (deg > 64) deg = 64;

  int s_i = 0;
  if (lane < deg) s_i = sorted_src[off + lane];
  ro_sh[w][lane] = s_i * CH;

  // logits + softmax (lane = edge) — per wave, no cross-wave dependency
  float ar[H];
#pragma unroll
  for (int hh = 0; hh < H; ++hh) ar[hh] = (lane < deg) ? asrc[s_i * H + hh] : 0.f;
#pragma unroll
  for (int hh = 0; hh < H; ++hh) {
    float v = ar[hh] + (live ? adst[node * H + hh] : 0.f);
    v = (v > 0.f) ? v : NEG_SLOPE * v;           // leaky_relu
    float lg = (lane < deg) ? v : -1e30f;
#pragma unroll
    for (int o = 32; o; o >>= 1) lg = fmaxf(lg, __shfl_xor(lg, o));
    float p = (lane < deg) ? expf(v - lg) : 0.f;
    float s = p;
#pragma unroll
    for (int o = 32; o; o >>= 1) s += __shfl_xor(s, o);
    p_sh[w][lane * H + hh] = p * (1.f / (s + 1e-16f));
  }
  __syncthreads();   // safety; each wave only touches its own LDS slice

  int chlane = lane % NCH;
  int slot = lane / NCH;
  int ch = (WPN == 2 ? w * WCH : 0) + chlane * CPT;
  int head = ch >> 7;  // /128

  float acc[CPT];
#pragma unroll
  for (int c = 0; c < CPT; ++c) acc[c] = 0.f;

  const float* pw = &p_sh[w][0];
  const int* ro = &ro_sh[w][0];
  auto body = [&](int e) {
    float wt = pw[e * H + head];
    uint4 u = *(const uint4*)(h + (size_t)(unsigned)ro[e] + ch);
    acc[0] += bf_lo(u.x) * wt;  acc[1] += bf_hi(u.x) * wt;
    acc[2] += bf_lo(u.y) * wt;  acc[3] += bf_hi(u.y) * wt;
    acc[4] += bf_lo(u.z) * wt;  acc[5] += bf_hi(u.z) * wt;
    acc[6] += bf_lo(u.w) * wt;  acc[7] += bf_hi(u.w) * wt;
  };
  int e = slot;
  for (; e + 7 * SLOTS < deg; e += 8 * SLOTS) {  // 8 gathers in flight per lane
    body(e); body(e + SLOTS); body(e + 2 * SLOTS); body(e + 3 * SLOTS);
    body(e + 4 * SLOTS); body(e + 5 * SLOTS); body(e + 6 * SLOTS); body(e + 7 * SLOTS);
  }
  for (; e + SLOTS < deg; e += 2 * SLOTS) { body(e); body(e + SLOTS); }
  for (; e < deg; e += SLOTS) body(e);

#pragma unroll
  for (int o = NCH; o < 64; o <<= 1)
#pragma unroll
    for (int c = 0; c < CPT; ++c) acc[c] += __shfl_xor(acc[c], o);

  if (live && slot == 0) {
    float r[CPT];
#pragma unroll
    for (int c = 0; c < CPT; ++c) {
      float t = acc[c] + bias[ch + c];
      if (apply_elu) t = (t > 0.f) ? t : (expf(t) - 1.f);
      r[c] = t;
    }
    store_vec<CPT>(&out[(size_t)node * CH + ch], r);
  }
}

// ---------------- launch ----------------
extern "C" void kernel_launch(void* const* d_in, const int* in_sizes, int n_in,
                              void* d_out, int out_size, void* d_ws, size_t ws_size,
                              hipStream_t stream) {
  const float* x      = (const float*)d_in[0];
  const int*   ei     = (const int*)d_in[1];
  const float* W1     = (const float*)d_in[2];
  const float* a_src1 = (const float*)d_in[3];
  const float* a_dst1 = (const float*)d_in[4];
  const float* b1     = (const float*)d_in[5];
  const float* W2     = (const float*)d_in[6];
  const float* a_src2 = (const float*)d_in[7];
  const float* a_dst2 = (const float*)d_in[8];
  const float* b2     = (const float*)d_in[9];
  float* out = (float*)d_out;

  // workspace layout (aliased by liveness):
  //   bufA: hmidb (live: agg1 -> gemm2)
  //   bufB: h1b (live: gemm1 -> agg1) then h2b (live: gemm2 -> agg2)
  float* ws   = (float*)d_ws;
  float* as1  = ws;                                  // N*4
  float* ad1  = as1 + N_NODES * H1;                  // N*4
  float* as2  = ad1 + N_NODES * H1;                  // N
  float* ad2  = as2 + N_NODES;                       // N
  unsigned short* bufA = (unsigned short*)(ad2 + N_NODES);        // N*512 bf16
  unsigned short* bufB = bufA + (size_t)N_NODES * 512;            // N*512 bf16
  unsigned short* hmidb = bufA;
  unsigned short* h1b   = bufB;
  unsigned short* h2b   = bufB;
  unsigned short* W1t   = bufB + (size_t)N_NODES * 512;           // 512*512 bf16
  unsigned short* W2t   = W1t + 512 * 512;                        // 128*512 bf16
  int* counts = (int*)(W2t + 128 * 512);             // N
  int* cursor = counts + N_NODES;                    // N
  int* offs   = cursor + N_NODES;                    // N+1
  int* ssrc   = offs + N_NODES + 1;                  // E_TOT
  int* part   = ssrc + E_TOT;                        // N
  int* bsum   = part + N_NODES;                      // nb+1

  constexpr int NB = (N_NODES + 255) / 256;          // 196 scan blocks
  constexpr int NRT = (N_NODES + 127) / 128;         // 391 row tiles
  constexpr int NRT8 = ((NRT + 7) / 8) * 8;          // 392 padded

  // --- counting sort of edges by dst ---
  zero_int_kernel<<<(N_NODES + 255) / 256, 256, 0, stream>>>(counts, N_NODES);
  hist_kernel<<<(E_TOT + 255) / 256, 256, 0, stream>>>(ei, counts);
  scan1_kernel<<<NB, 256, 0, stream>>>(counts, part, bsum, N_NODES);
  scan2_kernel<<<1, 256, 0, stream>>>(bsum, NB);
  scan3_kernel<<<NB, 256, 0, stream>>>(part, bsum, offs, cursor, N_NODES);
  scatter_kernel<<<(E_TOT + 255) / 256, 256, 0, stream>>>(ei, offs, cursor, ssrc);

  // --- weight casts (x cast is fused into gemm1) ---
  tcast_kernel<<<(512 * 512 + 255) / 256, 256, 0, stream>>>(W1, W1t, 512, 512);
  tcast_kernel<<<(512 * 128 + 255) / 256, 256, 0, stream>>>(W2, W2t, 512, 128);

  // --- layer 1: fused-cast GEMM (bf16 out) + alpha dots, then softmax-aggregate ---
  gemm_bf16_kernel<true, unsigned short><<<NRT8 * H1, 256, 0, stream>>>(
      x, W1t, h1b, a_src1, a_dst1, as1, ad1, N_NODES, 512, 512, H1, NRT);
  aggregate_kernel<4, 2, unsigned short><<<N_NODES, 128, 0, stream>>>(
      h1b, as1, ad1, offs, ssrc, b1, hmidb, 1);

  // --- layer 2 ---
  gemm_bf16_kernel<false, unsigned short><<<NRT8, 256, 0, stream>>>(
      hmidb, W2t, h2b, a_src2, a_dst2, as2, ad2, N_NODES, 128, 512, 1, NRT);
  aggregate_kernel<1, 1, float><<<(N_NODES + 1) / 2, 128, 0, stream>>>(
      h2b, as2, ad2, offs, ssrc, b2, out, 0);
}

// Round 9
// 469.978 us; speedup vs baseline: 1.1114x; 1.1114x over previous
//
#include <hip/hip_runtime.h>
#include <hip/hip_bf16.h>
#include <math.h>

#define NEG_SLOPE 0.2f

constexpr int N_NODES = 50000;
constexpr int F_IN    = 512;
constexpr int HID     = 128;
constexpr int H1      = 4;
constexpr int E_EDGES = 800000;
constexpr int E_TOT   = E_EDGES + N_NODES;  // 850000 (self loops appended)
constexpr int DEG_CAP = 64;                 // max in-degree (Poisson(16)+1; P(>=64)~1e-13)

typedef __attribute__((ext_vector_type(8))) short short8;     // 8 bf16 = 4 VGPRs (MFMA frag)
typedef __attribute__((ext_vector_type(4))) float floatx4;    // MFMA acc
typedef __attribute__((ext_vector_type(4))) unsigned short ushort4v;

// fp32 -> bf16 round-to-nearest-even (finite inputs)
__device__ __forceinline__ unsigned short f2bf(float f) {
  union { float f; unsigned int u; } v; v.f = f;
  unsigned int u = v.u + 0x7FFFu + ((v.u >> 16) & 1u);
  return (unsigned short)(u >> 16);
}
__device__ __forceinline__ float bf_lo(unsigned int u) {
  union { unsigned int u; float f; } v; v.u = u << 16; return v.f;
}
__device__ __forceinline__ float bf_hi(unsigned int u) {
  union { unsigned int u; float f; } v; v.u = u & 0xFFFF0000u; return v.f;
}

__device__ __forceinline__ void store_val(float* p, float v) { *p = v; }
__device__ __forceinline__ void store_val(unsigned short* p, float v) { *p = f2bf(v); }

template <int CPT>
__device__ __forceinline__ void store_vec(unsigned short* p, const float* v) {
#pragma unroll
  for (int c = 0; c < CPT; c += 4) {
    ushort4v o;
#pragma unroll
    for (int j = 0; j < 4; ++j) o[j] = f2bf(v[c + j]);
    *(ushort4v*)(p + c) = o;
  }
}
template <int CPT>
__device__ __forceinline__ void store_vec(float* p, const float* v) {
#pragma unroll
  for (int c = 0; c < CPT; c += 4) *(float4*)(p + c) = *(const float4*)(v + c);
}

__device__ __forceinline__ void async_load16(const void* g, void* lds) {
  __builtin_amdgcn_global_load_lds(
      (const __attribute__((address_space(1))) unsigned int*)g,
      (__attribute__((address_space(3))) unsigned int*)lds, 16, 0, 0);
}

// ---------------- prep: zero bucket counters + transpose-cast both weights ----------------
// One kernel, three index ranges (launch-count reduction: was 3 kernels).
__global__ void prep_kernel(const float* __restrict__ W1, const float* __restrict__ W2,
                            unsigned short* __restrict__ W1t, unsigned short* __restrict__ W2t,
                            int* __restrict__ cnt) {
  int i = blockIdx.x * 256 + threadIdx.x;
  if (i < N_NODES) cnt[i] = 0;
  int j = i - N_NODES;                     // W1 [512][512] -> W1t [n][k]
  if (j >= 0 && j < 512 * 512) {
    int n = j >> 9, k = j & 511;
    W1t[j] = f2bf(W1[k * 512 + n]);
  }
  int l = i - N_NODES - 512 * 512;         // W2 [512][128] -> W2t [n][k]
  if (l >= 0 && l < 128 * 512) {
    int n = l >> 9, k = l & 511;
    W2t[l] = f2bf(W2[k * 128 + n]);
  }
}

// ---------------- bucket build: no scan, no sort (was 6 kernels incl. hist/scan/scatter) ----
__global__ void fill_kernel(const int* __restrict__ ei, int* __restrict__ cnt,
                            int* __restrict__ adj) {
  int i = blockIdx.x * blockDim.x + threadIdx.x;
  if (i >= E_TOT) return;
  int s, d;
  if (i < E_EDGES) { s = ei[i]; d = ei[E_EDGES + i]; }
  else             { s = i - E_EDGES; d = s; }
  int pos = atomicAdd(&cnt[d], 1);
  if (pos < DEG_CAP) adj[d * DEG_CAP + pos] = s;  // guard is unreachable for this graph
}

// ---------------- bf16 MFMA GEMM + fused alpha-dot epilogue ----------------
// CVT_A: A is fp32, converted to bf16 during LDS staging (fuses the cast kernel).
// Grid is 1D, swizzled so the Hn head-blocks of a row-tile share an XCD (id mod 8).
template <bool CVT_A, typename OT>
__global__ __launch_bounds__(256) void gemm_bf16_kernel(
    const void* __restrict__ Araw, const unsigned short* __restrict__ Bt,
    OT* __restrict__ C, const float* __restrict__ a_srcp, const float* __restrict__ a_dstp,
    float* __restrict__ alpha_src, float* __restrict__ alpha_dst,
    int M, int N, int K, int Hn, int nRowTiles) {
  __shared__ unsigned short As[128 * 32];  // [row][k] 8 KB
  __shared__ unsigned short Bs[128 * 32];
  __shared__ float red_s[128][2];
  __shared__ float red_d[128][2];

  int grp = blockIdx.x / (8 * Hn);
  int w8 = blockIdx.x % (8 * Hn);
  int head = w8 >> 3;
  int rowTile = grp * 8 + (w8 & 7);
  if (rowTile >= nRowTiles) return;    // whole block exits together (uniform)
  int row0 = rowTile * 128;
  int col0 = head * 128;

  int tid = threadIdx.x;
  int lane = tid & 63, wave = tid >> 6;
  int wm = wave & 1, wn = wave >> 1;
  int l15 = lane & 15, quad = lane >> 4;

  floatx4 acc[4][4];
#pragma unroll
  for (int i = 0; i < 4; ++i)
#pragma unroll
    for (int j = 0; j < 4; ++j) acc[i][j] = (floatx4){0.f, 0.f, 0.f, 0.f};

  int seg_b = wave * 2;
  int r_in = (lane >> 2);
  int c8 = (lane & 3) * 8;

  for (int k0 = 0; k0 < K; k0 += 32) {
    // ---- B tile: async global->LDS (8 segments of 512B over 4 waves) ----
#pragma unroll
    for (int p = 0; p < 2; ++p) {
      int seg = seg_b + p;
      int r = seg * 16 + r_in;
      int gc = col0 + r;                        // N multiple of 128
      async_load16(Bt + (size_t)gc * K + k0 + c8, &Bs[seg * 512]);
    }
    // ---- A tile ----
    if constexpr (CVT_A) {
      // 128 rows x 32 k-elems = 1024 float4 slots; 256 thr x 4 iters.
      const float* Af = (const float*)Araw;
#pragma unroll
      for (int p = 0; p < 4; ++p) {
        int lin = tid + p * 256;            // 0..1023
        int r = lin >> 3;                   // 0..127
        int q = lin & 7;                    // 0..7 (k-quad of 4 fp32)
        int gr = row0 + r; if (gr >= M) gr = M - 1;
        float4 f = *(const float4*)(Af + (size_t)gr * K + k0 + q * 4);
        ushort4v o;
        o[0] = f2bf(f.x); o[1] = f2bf(f.y); o[2] = f2bf(f.z); o[3] = f2bf(f.w);
        *(ushort4v*)&As[r * 32 + q * 4] = o;
      }
    } else {
      const unsigned short* Ab = (const unsigned short*)Araw;
#pragma unroll
      for (int p = 0; p < 2; ++p) {
        int seg = seg_b + p;
        int r = seg * 16 + r_in;
        int gr = row0 + r; if (gr >= M) gr = M - 1;
        async_load16(Ab + (size_t)gr * K + k0 + c8, &As[seg * 512]);
      }
    }
    __syncthreads();

    short8 a[4], b[4];
#pragma unroll
    for (int mi = 0; mi < 4; ++mi)
      a[mi] = *(const short8*)&As[(wm * 64 + mi * 16 + l15) * 32 + quad * 8];
#pragma unroll
    for (int ni = 0; ni < 4; ++ni)
      b[ni] = *(const short8*)&Bs[(wn * 64 + ni * 16 + l15) * 32 + quad * 8];
#pragma unroll
    for (int mi = 0; mi < 4; ++mi)
#pragma unroll
      for (int ni = 0; ni < 4; ++ni)
        acc[mi][ni] = __builtin_amdgcn_mfma_f32_16x16x32_bf16(a[mi], b[ni], acc[mi][ni], 0, 0, 0);
    __syncthreads();
  }

  float a_s[4], a_d[4];
#pragma unroll
  for (int ni = 0; ni < 4; ++ni) {
    int cih = wn * 64 + ni * 16 + l15;
    a_s[ni] = a_srcp[head * HID + cih];
    a_d[ni] = a_dstp[head * HID + cih];
  }

#pragma unroll
  for (int mi = 0; mi < 4; ++mi) {
#pragma unroll
    for (int r = 0; r < 4; ++r) {
      int rloc = wm * 64 + mi * 16 + quad * 4 + r;
      int grow = row0 + rloc;
      float ps = 0.f, pd = 0.f;
#pragma unroll
      for (int ni = 0; ni < 4; ++ni) {
        float v = acc[mi][ni][r];
        ps += v * a_s[ni];
        pd += v * a_d[ni];
        if (grow < M) {
          int gcol = col0 + wn * 64 + ni * 16 + l15;
          store_val(&C[(size_t)grow * N + gcol], v);
        }
      }
#pragma unroll
      for (int off = 1; off < 16; off <<= 1) {
        ps += __shfl_xor(ps, off);
        pd += __shfl_xor(pd, off);
      }
      if (l15 == 0) { red_s[rloc][wn] = ps; red_d[rloc][wn] = pd; }
    }
  }
  __syncthreads();
  if (tid < 128) {
    int grow = row0 + tid;
    if (grow < M) {
      alpha_src[(size_t)grow * Hn + head] = red_s[tid][0] + red_s[tid][1];
      alpha_dst[(size_t)grow * Hn + head] = red_d[tid][0] + red_d[tid][1];
    }
  }
}

// ---------------- segment softmax + weighted aggregation: ONE WAVE PER NODE ----------------
// R7 structure (best measured: 133us). Edge list from fixed-capacity buckets adj[node*64+k].
// Lanes cover CH = H*128 channels with CPT=8 ch/thread; SLOTS = 64*8/CH edge slots.
template <int H, typename OT>
__global__ __launch_bounds__(64) void aggregate_kernel(
    const unsigned short* __restrict__ h, const float* __restrict__ asrc,
    const float* __restrict__ adst, const int* __restrict__ cnt,
    const int* __restrict__ adj, const float* __restrict__ bias,
    OT* __restrict__ out, int apply_elu) {
  constexpr int CPT = 8;
  constexpr int CH = H * HID;
  constexpr int NCH = CH / CPT;        // lanes covering channels
  constexpr int SLOTS = 64 / NCH;      // edge slots per wave
  __shared__ float p_sh[64 * H];
  __shared__ int ro_sh[64];            // src * CH (fits int: 50000*512)
  int node = blockIdx.x;
  int lane = threadIdx.x;
  int deg = cnt[node];
  if (deg > DEG_CAP) deg = DEG_CAP;

  int s_i = 0;
  if (lane < deg) s_i = adj[node * DEG_CAP + lane];
  ro_sh[lane] = s_i * CH;

  // logits + softmax (lane = edge)
  float ar[H];
#pragma unroll
  for (int hh = 0; hh < H; ++hh) ar[hh] = (lane < deg) ? asrc[s_i * H + hh] : 0.f;
#pragma unroll
  for (int hh = 0; hh < H; ++hh) {
    float v = ar[hh] + adst[node * H + hh];
    v = (v > 0.f) ? v : NEG_SLOPE * v;           // leaky_relu
    float lg = (lane < deg) ? v : -1e30f;
#pragma unroll
    for (int o = 32; o; o >>= 1) lg = fmaxf(lg, __shfl_xor(lg, o));
    float p = (lane < deg) ? expf(v - lg) : 0.f;
    float s = p;
#pragma unroll
    for (int o = 32; o; o >>= 1) s += __shfl_xor(s, o);
    p_sh[lane * H + hh] = p * (1.f / (s + 1e-16f));
  }
  __syncthreads();

  int chlane = lane % NCH;
  int slot = lane / NCH;
  int ch = chlane * CPT;
  int head = ch >> 7;  // /128

  float acc[CPT];
#pragma unroll
  for (int c = 0; c < CPT; ++c) acc[c] = 0.f;

  auto body = [&](int e) {
    float w = p_sh[e * H + head];
    uint4 u = *(const uint4*)(h + (size_t)(unsigned)ro_sh[e] + ch);
    acc[0] += bf_lo(u.x) * w;  acc[1] += bf_hi(u.x) * w;
    acc[2] += bf_lo(u.y) * w;  acc[3] += bf_hi(u.y) * w;
    acc[4] += bf_lo(u.z) * w;  acc[5] += bf_hi(u.z) * w;
    acc[6] += bf_lo(u.w) * w;  acc[7] += bf_hi(u.w) * w;
  };
  int e = slot;
  for (; e + 7 * SLOTS < deg; e += 8 * SLOTS) {  // 8 gathers in flight
    body(e); body(e + SLOTS); body(e + 2 * SLOTS); body(e + 3 * SLOTS);
    body(e + 4 * SLOTS); body(e + 5 * SLOTS); body(e + 6 * SLOTS); body(e + 7 * SLOTS);
  }
  for (; e + SLOTS < deg; e += 2 * SLOTS) { body(e); body(e + SLOTS); }
  for (; e < deg; e += SLOTS) body(e);

#pragma unroll
  for (int o = NCH; o < 64; o <<= 1)
#pragma unroll
    for (int c = 0; c < CPT; ++c) acc[c] += __shfl_xor(acc[c], o);

  if (slot == 0) {
    float r[CPT];
#pragma unroll
    for (int c = 0; c < CPT; ++c) {
      float t = acc[c] + bias[ch + c];
      if (apply_elu) t = (t > 0.f) ? t : (expf(t) - 1.f);
      r[c] = t;
    }
    store_vec<CPT>(&out[(size_t)node * CH + ch], r);
  }
}

// ---------------- launch (6 dispatches total; was 13) ----------------
extern "C" void kernel_launch(void* const* d_in, const int* in_sizes, int n_in,
                              void* d_out, int out_size, void* d_ws, size_t ws_size,
                              hipStream_t stream) {
  const float* x      = (const float*)d_in[0];
  const int*   ei     = (const int*)d_in[1];
  const float* W1     = (const float*)d_in[2];
  const float* a_src1 = (const float*)d_in[3];
  const float* a_dst1 = (const float*)d_in[4];
  const float* b1     = (const float*)d_in[5];
  const float* W2     = (const float*)d_in[6];
  const float* a_src2 = (const float*)d_in[7];
  const float* a_dst2 = (const float*)d_in[8];
  const float* b2     = (const float*)d_in[9];
  float* out = (float*)d_out;

  // workspace layout (aliased by liveness):
  //   bufA: hmidb (live: agg1 -> gemm2)
  //   bufB: h1b (live: gemm1 -> agg1) then h2b (live: gemm2 -> agg2)
  float* ws   = (float*)d_ws;
  float* as1  = ws;                                  // N*4
  float* ad1  = as1 + N_NODES * H1;                  // N*4
  float* as2  = ad1 + N_NODES * H1;                  // N
  float* ad2  = as2 + N_NODES;                       // N
  unsigned short* bufA = (unsigned short*)(ad2 + N_NODES);        // N*512 bf16
  unsigned short* bufB = bufA + (size_t)N_NODES * 512;            // N*512 bf16
  unsigned short* hmidb = bufA;
  unsigned short* h1b   = bufB;
  unsigned short* h2b   = bufB;
  unsigned short* W1t   = bufB + (size_t)N_NODES * 512;           // 512*512 bf16
  unsigned short* W2t   = W1t + 512 * 512;                        // 128*512 bf16
  int* cnt = (int*)(W2t + 128 * 512);                // N
  int* adj = cnt + N_NODES;                          // N*64

  constexpr int NRT = (N_NODES + 127) / 128;         // 391 row tiles
  constexpr int NRT8 = ((NRT + 7) / 8) * 8;          // 392 padded
  constexpr int PREP_ITEMS = N_NODES + 512 * 512 + 128 * 512;

  // --- prep (cnt zero + both weight transposes) & bucket build ---
  prep_kernel<<<(PREP_ITEMS + 255) / 256, 256, 0, stream>>>(W1, W2, W1t, W2t, cnt);
  fill_kernel<<<(E_TOT + 255) / 256, 256, 0, stream>>>(ei, cnt, adj);

  // --- layer 1: fused-cast GEMM (bf16 out) + alpha dots, then softmax-aggregate ---
  gemm_bf16_kernel<true, unsigned short><<<NRT8 * H1, 256, 0, stream>>>(
      x, W1t, h1b, a_src1, a_dst1, as1, ad1, N_NODES, 512, 512, H1, NRT);
  aggregate_kernel<4, unsigned short><<<N_NODES, 64, 0, stream>>>(
      h1b, as1, ad1, cnt, adj, b1, hmidb, 1);

  // --- layer 2 ---
  gemm_bf16_kernel<false, unsigned short><<<NRT8, 256, 0, stream>>>(
      hmidb, W2t, h2b, a_src2, a_dst2, as2, ad2, N_NODES, 128, 512, 1, NRT);
  aggregate_kernel<1, float><<<N_NODES, 64, 0, stream>>>(
      h2b, as2, ad2, cnt, adj, b2, out, 0);
}